// Round 3
// baseline (115.941 us; speedup 1.0000x reference)
//
#include <hip/hip_runtime.h>
#include <hip/hip_bf16.h>
#include <stdint.h>

#define BN_EPS 1e-3f

typedef __bf16 bf16x8 __attribute__((ext_vector_type(8)));
typedef float  f32x16 __attribute__((ext_vector_type(16)));

// Dims: B=256, F=64, Df=H=D=256, E=8. Tokens=16384; tile = 128 tokens (2 batch rows).
// Grid 256 = 128 tiles x 2 expert-halves (eh). eh parity == XCD parity -> each XCD caches 1.5MB.
// ws: [0,3.0M) packed weights bf16 | fold 32KB | wrt 2KB | wb 64KB
static constexpr size_t WS_FOLD_OFF = 24ull * 131072ull;
static constexpr size_t WS_WRT_OFF  = WS_FOLD_OFF + 32768ull;
static constexpr size_t WS_WB_OFF   = WS_WRT_OFF + 2048ull;

// ---------------- BN fold ----------------
__global__ __launch_bounds__(256) void fold_kernel(
    const float* __restrict__ b1, const float* __restrict__ g1, const float* __restrict__ be1,
    const float* __restrict__ m1, const float* __restrict__ v1,
    const float* __restrict__ b2, const float* __restrict__ g2, const float* __restrict__ be2,
    const float* __restrict__ m2, const float* __restrict__ v2,
    float* __restrict__ fold) {
  int i = blockIdx.x * 256 + threadIdx.x;
  if (i < 2048) {
    float s1 = g1[i] * rsqrtf(v1[i] + BN_EPS);
    fold[i]        = s1;
    fold[2048 + i] = (b1[i] - m1[i]) * s1 + be1[i];
    float s2 = g2[i] * rsqrtf(v2[i] + BN_EPS);
    fold[4096 + i] = s2;
    fold[6144 + i] = (b2[i] - m2[i]) * s2 + be2[i];
  }
}

// ---------------- Weight pack: fp32 [E][K][N] -> bf16 MFMA-frag order ----------------
__global__ __launch_bounds__(256) void pack_kernel(
    const float* __restrict__ W1, const float* __restrict__ W2, const float* __restrict__ Wo,
    __bf16* __restrict__ pk) {
  __shared__ float sl[16 * 256];
  int bid = blockIdx.x;             // 384 = 24 mats * 16 ks
  int m = bid >> 4, ks = bid & 15;
  int L = m >> 3, e = m & 7;
  const float* Ws = (L == 0 ? W1 : (L == 1 ? W2 : Wo)) + (size_t)e * 65536 + (size_t)ks * 16 * 256;
  int t = threadIdx.x;
#pragma unroll
  for (int it = 0; it < 4; ++it) {
    int el4 = it * 256 + t;
    float4 v = *reinterpret_cast<const float4*>(Ws + (size_t)el4 * 4);
    *reinterpret_cast<float4*>(&sl[el4 * 4]) = v;
  }
  __syncthreads();
#pragma unroll
  for (int it = 0; it < 2; ++it) {
    int task = it * 256 + t;        // nb(8) x lane(64)
    int nb = task >> 6, l = task & 63;
    int colb = nb * 32 + (l & 31);
    int krow = (l >> 5) * 8;
    union { __bf16 h[8]; int4 v; } u;
#pragma unroll
    for (int i = 0; i < 8; ++i) u.h[i] = (__bf16)sl[(krow + i) * 256 + colb];
    size_t off = ((size_t)(m * 8 + nb) * 16 + ks) * 512 + (size_t)l * 8;
    *reinterpret_cast<int4*>(pk + off) = u.v;
  }
}

// ---------------- Routing + wb = wrt @ bo ----------------
__global__ __launch_bounds__(256) void route_kernel(
    const float* __restrict__ x, const float* __restrict__ Wr, const float* __restrict__ br,
    const float* __restrict__ bo, float* __restrict__ wrt, float* __restrict__ wb) {
  __shared__ float4 part[4][64];
  __shared__ float feat[256];
  __shared__ float lg[8];
  __shared__ float wsm[8];
  int f = blockIdx.x, t = threadIdx.x;
  int bq = t >> 6, dq = t & 63;
  float4 s = {0.f, 0.f, 0.f, 0.f};
  const float* xp = x + (size_t)(bq * 64) * 16384 + f * 256 + dq * 4;
  for (int bi = 0; bi < 64; ++bi) {
    float4 v = *reinterpret_cast<const float4*>(xp + (size_t)bi * 16384);
    s.x += v.x; s.y += v.y; s.z += v.z; s.w += v.w;
  }
  part[bq][dq] = s;
  __syncthreads();
  if (t < 64) {
    float4 a = part[0][t], b = part[1][t], c = part[2][t], d = part[3][t];
    float4 r;
    r.x = (a.x + b.x) + (c.x + d.x); r.y = (a.y + b.y) + (c.y + d.y);
    r.z = (a.z + b.z) + (c.z + d.z); r.w = (a.w + b.w) + (c.w + d.w);
    r.x *= (1.f/256.f); r.y *= (1.f/256.f); r.z *= (1.f/256.f); r.w *= (1.f/256.f);
    *reinterpret_cast<float4*>(&feat[t * 4]) = r;
  }
  __syncthreads();
  if (t < 8) {
    float a = br[t];
    for (int d = 0; d < 256; ++d) a += feat[d] * Wr[d * 8 + t];
    lg[t] = a;
  }
  __syncthreads();
  if (t == 0) {
    float mx = lg[0];
#pragma unroll
    for (int e = 1; e < 8; ++e) mx = fmaxf(mx, lg[e]);
    float ex[8]; float sum = 0.f;
#pragma unroll
    for (int e = 0; e < 8; ++e) { ex[e] = expf(lg[e] - mx); sum += ex[e]; }
    float inv = 1.0f / sum;
#pragma unroll
    for (int e = 0; e < 8; ++e) { float v = ex[e] * inv; wsm[e] = v; wrt[f * 8 + e] = v; }
  }
  __syncthreads();
  float o = 0.f;
#pragma unroll
  for (int e = 0; e < 8; ++e) o += wsm[e] * bo[e * 256 + t];
  wb[f * 256 + t] = o;
}

// ---------------- Main fused MoE ----------------
// 512 thr = 8 waves; wave w owns 32 output cols (nb=w), all 128 tokens (4 mt tiles).
// LDS frag-major: buf[fr=k>>3][token] 16B units; fr f holds k in [8f,8f+8).
// Swapped phases L0/L1: acc = mfma(Wfrag, actfrag) -> rows=h-cols, cols=tokens.
__device__ __forceinline__ void phase_swapped(
    const char* __restrict__ src, char* __restrict__ dst,
    const __bf16* __restrict__ pb, const float* __restrict__ sA, const float* __restrict__ cA,
    int l, int l31, int hi, int w) {
  f32x16 acc[4];
#pragma unroll
  for (int mt = 0; mt < 4; ++mt)
#pragma unroll
    for (int r = 0; r < 16; ++r) acc[mt][r] = 0.f;
  bf16x8 bq = *reinterpret_cast<const bf16x8*>(pb + (size_t)l * 8);
#pragma unroll
  for (int ks = 0; ks < 16; ++ks) {
    bf16x8 bn = (ks < 15) ? *reinterpret_cast<const bf16x8*>(pb + (size_t)(ks + 1) * 512 + (size_t)l * 8) : bq;
#pragma unroll
    for (int mt = 0; mt < 4; ++mt) {
      bf16x8 xf = *reinterpret_cast<const bf16x8*>(src + (((2 * ks + hi) * 128 + mt * 32 + l31) << 4));
      acc[mt] = __builtin_amdgcn_mfma_f32_32x32x16_bf16(bq, xf, acc[mt], 0, 0, 0);
    }
    bq = bn;
  }
  __syncthreads();   // all waves done reading src (in-place / prev-phase safety)
#pragma unroll
  for (int g = 0; g < 4; ++g) {
    float4 s4 = *reinterpret_cast<const float4*>(sA + 8 * g);
    float4 c4 = *reinterpret_cast<const float4*>(cA + 8 * g);
#pragma unroll
    for (int mt = 0; mt < 4; ++mt) {
      union { __bf16 h[4]; uint2 u; } p;
#pragma unroll
      for (int j = 0; j < 4; ++j) {
        float sj = (&s4.x)[j], cj = (&c4.x)[j];
        p.h[j] = (__bf16)fmaxf(acc[mt][4 * g + j] * sj + cj, 0.f);
      }
      int addr = (((w * 4 + g) * 128 + mt * 32 + l31) << 4) + hi * 8;
      *reinterpret_cast<uint2*>(dst + addr) = p.u;
    }
  }
  __syncthreads();   // h visible to all
}

__global__ __launch_bounds__(512, 2) void moe_kernel(
    const float* __restrict__ x, const __bf16* __restrict__ pk,
    const float* __restrict__ fold, const float* __restrict__ wrt,
    const float* __restrict__ wb, float* __restrict__ out) {
  __shared__ char xb[65536];
  __shared__ char hb[65536];
  __shared__ float wrts[512];
  const int tid = threadIdx.x;
  const int l = tid & 63, w = tid >> 6;
  const int l31 = l & 31, hi = l >> 5;
  const int bid = blockIdx.x;
  const int tile = bid >> 1, eh = bid & 1;

  // ---- stage x -> bf16 LDS frag-major (wave-local, conflict-free) ----
  {
    const float* xg = x + (size_t)tile * 32768;
    int tok = w * 16 + (l & 15);
    int kc = l >> 4;
#pragma unroll
    for (int i = 0; i < 8; ++i) {
      int fr = kc * 8 + i;
      const float* src = xg + (size_t)tok * 256 + fr * 8;
      float4 v0 = *reinterpret_cast<const float4*>(src);
      float4 v1 = *reinterpret_cast<const float4*>(src + 4);
      union { __bf16 h[8]; int4 v; } u;
      u.h[0] = (__bf16)v0.x; u.h[1] = (__bf16)v0.y; u.h[2] = (__bf16)v0.z; u.h[3] = (__bf16)v0.w;
      u.h[4] = (__bf16)v1.x; u.h[5] = (__bf16)v1.y; u.h[6] = (__bf16)v1.z; u.h[7] = (__bf16)v1.w;
      *reinterpret_cast<int4*>(xb + ((fr * 128 + tok) << 4)) = u.v;
    }
  }
  if (tid < 512) wrts[tid] = wrt[tid];

  f32x16 outacc[4];
#pragma unroll
  for (int mt = 0; mt < 4; ++mt)
#pragma unroll
    for (int r = 0; r < 16; ++r) outacc[mt][r] = 0.f;

  __syncthreads();

#pragma unroll 1
  for (int ep = 0; ep < 4; ++ep) {
    const int e = eh * 4 + ep;
    // L0: reads xb (never written again), writes hb
    phase_swapped(xb, hb, pk + (size_t)((0 * 8 + e) * 8 + w) * 8192,
                  fold + 0 * 4096 + e * 256 + w * 32 + 4 * hi,
                  fold + 0 * 4096 + 2048 + e * 256 + w * 32 + 4 * hi, l, l31, hi, w);
    // L1: reads hb, writes hb in place (barrier inside between read & write)
    phase_swapped(hb, hb, pk + (size_t)((1 * 8 + e) * 8 + w) * 8192,
                  fold + 1 * 4096 + e * 256 + w * 32 + 4 * hi,
                  fold + 1 * 4096 + 2048 + e * 256 + w * 32 + 4 * hi, l, l31, hi, w);
    // L2 (normal): acc = mfma(hfrag, Wofrag); rows=tokens, cols=d
    {
      f32x16 acc[4];
#pragma unroll
      for (int mt = 0; mt < 4; ++mt)
#pragma unroll
        for (int r = 0; r < 16; ++r) acc[mt][r] = 0.f;
      const __bf16* pb = pk + (size_t)((2 * 8 + e) * 8 + w) * 8192;
      bf16x8 bq = *reinterpret_cast<const bf16x8*>(pb + (size_t)l * 8);
#pragma unroll
      for (int ks = 0; ks < 16; ++ks) {
        bf16x8 bn = (ks < 15) ? *reinterpret_cast<const bf16x8*>(pb + (size_t)(ks + 1) * 512 + (size_t)l * 8) : bq;
#pragma unroll
        for (int mt = 0; mt < 4; ++mt) {
          bf16x8 hf = *reinterpret_cast<const bf16x8*>(hb + (((2 * ks + hi) * 128 + mt * 32 + l31) << 4));
          acc[mt] = __builtin_amdgcn_mfma_f32_32x32x16_bf16(hf, bq, acc[mt], 0, 0, 0);
        }
        bq = bn;
      }
#pragma unroll
      for (int mt = 0; mt < 4; ++mt) {
#pragma unroll
        for (int r = 0; r < 16; ++r) {
          int row = mt * 32 + 4 * hi + (r & 3) + 8 * (r >> 2);
          outacc[mt][r] += wrts[(row & 63) * 8 + e] * acc[mt][r];
        }
      }
      // no barrier: next L0's post-MFMA barrier covers these reads
    }
  }

  // ---- combine: 2 commutative fp32 atomics per element (deterministic) ----
  float* og = out + (size_t)tile * 32768;
  const int col = w * 32 + l31;
#pragma unroll
  for (int mt = 0; mt < 4; ++mt) {
#pragma unroll
    for (int r = 0; r < 16; ++r) {
      int row = mt * 32 + 4 * hi + (r & 3) + 8 * (r >> 2);
      float v = outacc[mt][r];
      if (eh == 0) v += wb[(row & 63) * 256 + col];
      unsafeAtomicAdd(og + row * 256 + col, v);
    }
  }
}

extern "C" void kernel_launch(void* const* d_in, const int* in_sizes, int n_in,
                              void* d_out, int out_size, void* d_ws, size_t ws_size,
                              hipStream_t stream) {
  const float* x   = (const float*)d_in[0];
  const float* Wr  = (const float*)d_in[1];
  const float* br  = (const float*)d_in[2];
  const float* W1  = (const float*)d_in[3];
  const float* b1  = (const float*)d_in[4];
  const float* g1  = (const float*)d_in[5];
  const float* be1 = (const float*)d_in[6];
  const float* m1  = (const float*)d_in[7];
  const float* v1  = (const float*)d_in[8];
  const float* W2  = (const float*)d_in[9];
  const float* b2  = (const float*)d_in[10];
  const float* g2  = (const float*)d_in[11];
  const float* be2 = (const float*)d_in[12];
  const float* m2  = (const float*)d_in[13];
  const float* v2  = (const float*)d_in[14];
  const float* Wo  = (const float*)d_in[15];
  const float* bo  = (const float*)d_in[16];
  float* out = (float*)d_out;

  __bf16* pk  = (__bf16*)d_ws;
  float* fold = (float*)((char*)d_ws + WS_FOLD_OFF);
  float* wrt  = (float*)((char*)d_ws + WS_WRT_OFF);
  float* wb   = (float*)((char*)d_ws + WS_WB_OFF);

  hipMemsetAsync(out, 0, (size_t)out_size * sizeof(float), stream);
  hipLaunchKernelGGL(fold_kernel, dim3(8), dim3(256), 0, stream,
                     b1, g1, be1, m1, v1, b2, g2, be2, m2, v2, fold);
  hipLaunchKernelGGL(pack_kernel, dim3(384), dim3(256), 0, stream, W1, W2, Wo, pk);
  hipLaunchKernelGGL(route_kernel, dim3(64), dim3(256), 0, stream, x, Wr, br, bo, wrt, wb);
  hipLaunchKernelGGL(moe_kernel, dim3(256), dim3(512), 0, stream, x, pk, fold, wrt, wb, out);
}